// Round 16
// baseline (639.065 us; speedup 1.0000x reference)
//
#include <hip/hip_runtime.h>

#define N_NODES 50000
#define N_EDGES 800000
#define HID 128
#define NP 391           // node partitions of 128 nodes
#define CAPP 2816        // partition capacity: mean 2048 + 17 sigma
#define PC_STRIDE 32     // pcnt padding: 128B per counter
#define P1_BLOCKS 128
#define EPB ((N_EDGES + P1_BLOCKS - 1) / P1_BLOCKS)  // 6250 edges/block
#define GEMM_BLOCKS ((N_NODES + 63) / 64)            // 782
#define NSL 4            // column slices (32 cols each)
#define SLICE4_U16 ((size_t)N_NODES * 32)

typedef float f4v __attribute__((ext_vector_type(4)));
typedef short s8v __attribute__((ext_vector_type(8)));
typedef unsigned short u16;

__device__ __forceinline__ u16 f2bf(float f) {  // RNE fp32 -> bf16
  union { float f; unsigned u; } v;
  v.f = f;
  const unsigned r = v.u + 0x7FFFu + ((v.u >> 16) & 1u);
  return (u16)(r >> 16);
}
__device__ __forceinline__ float bf2f(u16 h) {
  union { unsigned u; float f; } v;
  v.u = ((unsigned)h) << 16;
  return v.f;
}

// ---------------- fused init: W fp32->bf16 (blocks 0..63) + zero pcnt ----------------
__global__ __launch_bounds__(256) void init_k(const float* __restrict__ W,
                                              u16* __restrict__ Wb,
                                              int* __restrict__ pcnt) {
  const int b = blockIdx.x;
  if (b < 64) {
    const int i = b * 256 + threadIdx.x;
    Wb[i] = f2bf(W[i]);
  } else {
    const int i = (b - 64) * 256 + threadIdx.x;
    if (i < NP * PC_STRIDE) pcnt[i] = 0;
  }
}

// ---------------- FUSED (R10-exact): scatter (blocks 0..127) + MFMA GEMM ----------------
__global__ __launch_bounds__(256) void sg_k(const int* __restrict__ EI,
                                            int* __restrict__ pcnt,
                                            unsigned* __restrict__ part,
                                            const float* __restrict__ X,
                                            const u16* __restrict__ Wb,
                                            const float* __restrict__ Bias,
                                            u16* __restrict__ Hb) {
  __shared__ int hist[NP], base[NP], cur[NP];
  if (blockIdx.x < P1_BLOCKS) {
    const int t = threadIdx.x;
    for (int i = t; i < NP; i += 256) { hist[i] = 0; cur[i] = 0; }
    __syncthreads();
    const int e0 = blockIdx.x * EPB;
    const int e1 = min(e0 + EPB, N_EDGES);
    for (int e = e0 + t; e < e1; e += 256) atomicAdd(&hist[EI[e] >> 7], 1);
    __syncthreads();
    for (int i = t; i < NP; i += 256) {
      const int h = hist[i];
      int bs = 0;
      if (h > 0) bs = atomicAdd(pcnt + i * PC_STRIDE, h);
      base[i] = i * CAPP + min(bs, CAPP);
    }
    __syncthreads();
    for (int e = e0 + t; e < e1; e += 256) {
      const int dst = EI[e];
      const int src = EI[N_EDGES + e];
      const int p = dst >> 7;
      const int pos = atomicAdd(&cur[p], 1);
      const int gpos = base[p] + pos;
      if (gpos < (p + 1) * CAPP)
        part[gpos] = ((unsigned)src << 7) | (unsigned)(dst & 127);
    }
    return;
  }
  // ---- GEMM part: Hb_t[sl][row][32] = bf16(X @ W^T + bias) ----
  const int gb = blockIdx.x - P1_BLOCKS;
  const int lane = threadIdx.x & 63;
  const int wv = threadIdx.x >> 6;
  const int i0 = gb * 64 + wv * 16;
  const int r16 = lane & 15;
  const int kb = lane >> 4;

  int arow = i0 + r16;
  if (arow >= N_NODES) arow = N_NODES - 1;  // clamp reads; stores guarded

  s8v a[4];
#pragma unroll
  for (int kc = 0; kc < 4; ++kc) {
    const int k0 = kc * 32 + kb * 8;
    const float4 x0 = *(const float4*)(X + (size_t)arow * HID + k0);
    const float4 x1 = *(const float4*)(X + (size_t)arow * HID + k0 + 4);
    s8v tv;
    tv[0] = (short)f2bf(x0.x); tv[1] = (short)f2bf(x0.y);
    tv[2] = (short)f2bf(x0.z); tv[3] = (short)f2bf(x0.w);
    tv[4] = (short)f2bf(x1.x); tv[5] = (short)f2bf(x1.y);
    tv[6] = (short)f2bf(x1.z); tv[7] = (short)f2bf(x1.w);
    a[kc] = tv;
  }

  f4v acc[8];
#pragma unroll
  for (int jt = 0; jt < 8; ++jt) acc[jt] = (f4v){0.f, 0.f, 0.f, 0.f};

#pragma unroll
  for (int jt = 0; jt < 8; ++jt) {
    const int j = jt * 16 + r16;
#pragma unroll
    for (int kc = 0; kc < 4; ++kc) {
      const int k0 = kc * 32 + kb * 8;
      const s8v bb = *(const s8v*)(Wb + (size_t)j * HID + k0);
      acc[jt] = __builtin_amdgcn_mfma_f32_16x16x32_bf16(a[kc], bb, acc[jt], 0, 0, 0);
    }
  }

#pragma unroll
  for (int jt = 0; jt < 8; ++jt) {
    const int sl = jt >> 1;
    const int c = (jt & 1) * 16 + r16;  // col within 32-col slice
    const float bias = Bias[jt * 16 + r16];
#pragma unroll
    for (int r = 0; r < 4; ++r) {
      const int row = i0 + kb * 4 + r;
      if (row < N_NODES)
        Hb[(size_t)sl * SLICE4_U16 + (size_t)row * 32 + c] = f2bf(acc[jt][r] + bias);
    }
  }
}

// ---------------- direct aggregate: unsorted partition entries -> LDS fp32 tile ----------------
// block = one (partition p, slice sl) unit; sl = blockIdx&3 keeps each XCD on
// ONE 3.2MB L2-resident Hb slice. Scan the <=2816 packed entries once:
// accum[dl][c] += Hb_slice[src][c] via LDS atomics (pad 33 spreads banks;
// random dl -> ~2-way conflict, free). deg counted exactly. Epilogue:
// OUT[:, sl*32..] = (accum + self) / (deg+1). Replaces p2csr + gather4.
__global__ __launch_bounds__(256) void agg_k(const unsigned* __restrict__ part,
                                             const int* __restrict__ pcnt,
                                             const u16* __restrict__ Hb,
                                             float* __restrict__ OUT) {
  __shared__ float accum[128][33];
  __shared__ int cnt[128];
  const int sl = blockIdx.x & 3;
  const int p = blockIdx.x >> 2;
  const int t = threadIdx.x;

  float* af = &accum[0][0];
  for (int i = t; i < 128 * 33; i += 256) af[i] = 0.f;
  if (t < 128) cnt[t] = 0;
  __syncthreads();

  const u16* Hbs = Hb + (size_t)sl * SLICE4_U16;
  const int pb = p * CAPP;
  const int cn = min(pcnt[p * PC_STRIDE], CAPP);
  const int ei = t >> 2;   // entry slot within 64-entry group
  const int lp = t & 3;    // lane-part: 8 cols (16B) of the 32-col slice

  for (int b0 = 0; b0 < cn; b0 += 256) {
    unsigned pv[4];
    bool ok[4];
#pragma unroll
    for (int k = 0; k < 4; ++k) {
      const int i = b0 + k * 64 + ei;
      ok[k] = i < cn;
      pv[k] = ok[k] ? part[pb + i] : 0u;
    }
    s8v row[4];
#pragma unroll
    for (int k = 0; k < 4; ++k) {
      const int s = (int)(pv[k] >> 7);
      row[k] = ok[k] ? *(const s8v*)(Hbs + (size_t)s * 32 + lp * 8)
                     : (s8v){0, 0, 0, 0, 0, 0, 0, 0};
    }
#pragma unroll
    for (int k = 0; k < 4; ++k) {
      if (!ok[k]) continue;
      const int dl = (int)(pv[k] & 127u);
      if (lp == 0) atomicAdd(&cnt[dl], 1);
#pragma unroll
      for (int c = 0; c < 8; ++c)
        atomicAdd(&accum[dl][lp * 8 + c], bf2f((u16)row[k][c]));
    }
  }
  __syncthreads();

  // epilogue: 2 threads per node, 16 cols each
  const int nl = t >> 1;
  const int hf = t & 1;
  const int n = p * 128 + nl;
  if (n < N_NODES) {
    const float inv = 1.0f / (float)(cnt[nl] + 1);
    const s8v h0 = *(const s8v*)(Hbs + (size_t)n * 32 + hf * 16);
    const s8v h1 = *(const s8v*)(Hbs + (size_t)n * 32 + hf * 16 + 8);
    f4v o0, o1, o2, o3;
#pragma unroll
    for (int c = 0; c < 4; ++c) {
      o0[c] = (accum[nl][hf * 16 + c]      + bf2f((u16)h0[c]))     * inv;
      o1[c] = (accum[nl][hf * 16 + 4 + c]  + bf2f((u16)h0[4 + c])) * inv;
      o2[c] = (accum[nl][hf * 16 + 8 + c]  + bf2f((u16)h1[c]))     * inv;
      o3[c] = (accum[nl][hf * 16 + 12 + c] + bf2f((u16)h1[4 + c])) * inv;
    }
    float* po = OUT + (size_t)n * HID + sl * 32 + hf * 16;
    *(f4v*)(po) = o0;
    *(f4v*)(po + 4) = o1;
    *(f4v*)(po + 8) = o2;
    *(f4v*)(po + 12) = o3;
  }
}

extern "C" void kernel_launch(void* const* d_in, const int* in_sizes, int n_in,
                              void* d_out, int out_size, void* d_ws, size_t ws_size,
                              hipStream_t stream) {
  const float* X = (const float*)d_in[0];     // [N_NODES, HID]
  const int* EI = (const int*)d_in[1];        // [2, N_EDGES]
  const float* W = (const float*)d_in[2];     // [HID, HID]
  const float* Bias = (const float*)d_in[3];  // [HID]

  float* OUT = (float*)d_out;

  // ws layout (bytes):
  //   Hb_t  @ 0          : 4*50000*32*2 = 12,800,000
  //   part  @ 12,800,000 : 391*2816*4   =  4,404,224
  //   pcnt  @ 17,204,224 : 391*32*4     =     50,048
  //   Wb    @ 17,254,272 : 16384*2      =     32,768   (end 17,287,040)
  char* ws = (char*)d_ws;
  u16* Hb = (u16*)(ws);
  unsigned* part = (unsigned*)(ws + 12800000);
  int* pcnt = (int*)(ws + 17204224);
  u16* Wb = (u16*)(ws + 17254272);

  init_k<<<64 + (NP * PC_STRIDE + 255) / 256, 256, 0, stream>>>(W, Wb, pcnt);
  // fused (R10-exact): blocks 0..127 = scatter; 128.. = MFMA gemm
  sg_k<<<P1_BLOCKS + GEMM_BLOCKS, 256, 0, stream>>>(EI, pcnt, part, X, Wb, Bias, Hb);
  // direct aggregate replaces p2csr + gather4
  agg_k<<<NP * NSL, 256, 0, stream>>>(part, pcnt, Hb, OUT);
}

// Round 17
// 88.749 us; speedup vs baseline: 7.2008x; 7.2008x over previous
//
#include <hip/hip_runtime.h>

#define N_NODES 50000
#define N_EDGES 800000
#define HID 128
#define NP 391           // node partitions of 128 nodes
#define CAPP 2816        // partition capacity: mean 2048 + 17 sigma
#define PC_STRIDE 32     // pcnt padding: 128B per counter
#define P1_BLOCKS 128
#define EPB ((N_EDGES + P1_BLOCKS - 1) / P1_BLOCKS)  // 6250 edges/block
#define GEMM_BLOCKS ((N_NODES + 63) / 64)            // 782
#define NSL 4            // column slices (32 cols each)
#define SLICE4_U16 ((size_t)N_NODES * 32)

typedef float f4v __attribute__((ext_vector_type(4)));
typedef short s8v __attribute__((ext_vector_type(8)));
typedef unsigned short u16;

__device__ __forceinline__ u16 f2bf(float f) {  // RNE fp32 -> bf16
  union { float f; unsigned u; } v;
  v.f = f;
  const unsigned r = v.u + 0x7FFFu + ((v.u >> 16) & 1u);
  return (u16)(r >> 16);
}
__device__ __forceinline__ float bf2f(u16 h) {
  union { unsigned u; float f; } v;
  v.u = ((unsigned)h) << 16;
  return v.f;
}

// ---------------- fused init: W fp32->bf16 (blocks 0..63) + zero pcnt ----------------
__global__ __launch_bounds__(256) void init_k(const float* __restrict__ W,
                                              u16* __restrict__ Wb,
                                              int* __restrict__ pcnt) {
  const int b = blockIdx.x;
  if (b < 64) {
    const int i = b * 256 + threadIdx.x;
    Wb[i] = f2bf(W[i]);
  } else {
    const int i = (b - 64) * 256 + threadIdx.x;
    if (i < NP * PC_STRIDE) pcnt[i] = 0;
  }
}

// ---------------- FUSED (R10-exact + NT part store): scatter (0..127) + MFMA GEMM ----------------
__global__ __launch_bounds__(256) void sg_k(const int* __restrict__ EI,
                                            int* __restrict__ pcnt,
                                            unsigned* __restrict__ part,
                                            const float* __restrict__ X,
                                            const u16* __restrict__ Wb,
                                            const float* __restrict__ Bias,
                                            u16* __restrict__ Hb) {
  __shared__ int hist[NP], base[NP], cur[NP];
  if (blockIdx.x < P1_BLOCKS) {
    const int t = threadIdx.x;
    for (int i = t; i < NP; i += 256) { hist[i] = 0; cur[i] = 0; }
    __syncthreads();
    const int e0 = blockIdx.x * EPB;
    const int e1 = min(e0 + EPB, N_EDGES);
    for (int e = e0 + t; e < e1; e += 256) atomicAdd(&hist[EI[e] >> 7], 1);
    __syncthreads();
    for (int i = t; i < NP; i += 256) {
      const int h = hist[i];
      int bs = 0;
      if (h > 0) bs = atomicAdd(pcnt + i * PC_STRIDE, h);
      base[i] = i * CAPP + min(bs, CAPP);
    }
    __syncthreads();
    for (int e = e0 + t; e < e1; e += 256) {
      const int dst = EI[e];
      const int src = EI[N_EDGES + e];
      const int p = dst >> 7;
      const int pos = atomicAdd(&cur[p], 1);
      const int gpos = base[p] + pos;
      if (gpos < (p + 1) * CAPP)
        // nontemporal: bypass L2 -> no cross-XCD line ping-pong on the
        // randomly-scattered 4B writes (R15: 2-3x write amplification).
        __builtin_nontemporal_store(
            ((unsigned)src << 7) | (unsigned)(dst & 127), part + gpos);
    }
    return;
  }
  // ---- GEMM part: Hb_t[sl][row][32] = bf16(X @ W^T + bias) ----
  const int gb = blockIdx.x - P1_BLOCKS;
  const int lane = threadIdx.x & 63;
  const int wv = threadIdx.x >> 6;
  const int i0 = gb * 64 + wv * 16;
  const int r16 = lane & 15;
  const int kb = lane >> 4;

  int arow = i0 + r16;
  if (arow >= N_NODES) arow = N_NODES - 1;  // clamp reads; stores guarded

  s8v a[4];
#pragma unroll
  for (int kc = 0; kc < 4; ++kc) {
    const int k0 = kc * 32 + kb * 8;
    const float4 x0 = *(const float4*)(X + (size_t)arow * HID + k0);
    const float4 x1 = *(const float4*)(X + (size_t)arow * HID + k0 + 4);
    s8v tv;
    tv[0] = (short)f2bf(x0.x); tv[1] = (short)f2bf(x0.y);
    tv[2] = (short)f2bf(x0.z); tv[3] = (short)f2bf(x0.w);
    tv[4] = (short)f2bf(x1.x); tv[5] = (short)f2bf(x1.y);
    tv[6] = (short)f2bf(x1.z); tv[7] = (short)f2bf(x1.w);
    a[kc] = tv;
  }

  f4v acc[8];
#pragma unroll
  for (int jt = 0; jt < 8; ++jt) acc[jt] = (f4v){0.f, 0.f, 0.f, 0.f};

#pragma unroll
  for (int jt = 0; jt < 8; ++jt) {
    const int j = jt * 16 + r16;
#pragma unroll
    for (int kc = 0; kc < 4; ++kc) {
      const int k0 = kc * 32 + kb * 8;
      const s8v bb = *(const s8v*)(Wb + (size_t)j * HID + k0);
      acc[jt] = __builtin_amdgcn_mfma_f32_16x16x32_bf16(a[kc], bb, acc[jt], 0, 0, 0);
    }
  }

#pragma unroll
  for (int jt = 0; jt < 8; ++jt) {
    const int sl = jt >> 1;
    const int c = (jt & 1) * 16 + r16;  // col within 32-col slice
    const float bias = Bias[jt * 16 + r16];
#pragma unroll
    for (int r = 0; r < 4; ++r) {
      const int row = i0 + kb * 4 + r;
      if (row < N_NODES)
        Hb[(size_t)sl * SLICE4_U16 + (size_t)row * 32 + c] = f2bf(acc[jt][r] + bias);
    }
  }
}

// ---------------- per-partition CSR build (R10-exact) ----------------
__global__ __launch_bounds__(256) void p2csr_k(const unsigned* __restrict__ part,
                                               const int* __restrict__ pcnt,
                                               int* __restrict__ colidx,
                                               int2* __restrict__ rp2) {
  __shared__ int cnt[128], rs[129], cur[128];
  const int p = blockIdx.x;
  const int t = threadIdx.x;
  const int n0 = p * 128;
  const int nn = min(128, N_NODES - n0);
  const int gb = p * CAPP;
  const int ge = gb + min(pcnt[p * PC_STRIDE], CAPP);
  if (t < 128) cnt[t] = 0;
  __syncthreads();
  for (int i = gb + t; i < ge; i += 256) atomicAdd(&cnt[part[i] & 127u], 1);
  __syncthreads();
  if (t == 0) {
    int acc = 0;
    for (int i = 0; i < 128; ++i) { rs[i] = acc; acc += cnt[i]; }
    rs[128] = acc;
  }
  __syncthreads();
  if (t < 128) cur[t] = rs[t];
  if (t < nn) rp2[n0 + t] = make_int2(gb + rs[t], cnt[t]);
  __syncthreads();
  for (int i = gb + t; i < ge; i += 256) {
    const unsigned v = part[i];
    const int pos = atomicAdd(&cur[v & 127u], 1);
    colidx[gb + pos] = (int)(v >> 7);
  }
}

// ---------------- sliced CSR gather (R10-exact) ----------------
__global__ __launch_bounds__(256) void gather4_k(const u16* __restrict__ Hb,
                                                 const int* __restrict__ colidx,
                                                 const int2* __restrict__ rp2,
                                                 float* __restrict__ OUT) {
  const int slice = blockIdx.x & 3;
  const int nb = blockIdx.x >> 2;
  const int wv = threadIdx.x >> 6;
  const int lane = threadIdx.x & 63;
  const int q = lane >> 2;   // node slot within wave (0..15)
  const int sl4 = lane & 3;  // lane within node group
  const int node = (nb * 4 + wv) * 16 + q;
  const bool valid = node < N_NODES;
  const int nd = valid ? node : 0;
  const int2 bd = rp2[nd];
  const int b0 = bd.x;
  const int deg = bd.y;
  const u16* Hbs = Hb + (size_t)slice * SLICE4_U16;
  const int c0 = sl4 * 8;  // u16 offset within 32-col slice (16B per lane)

  int src[8];
#pragma unroll
  for (int r = 0; r < 8; ++r) {
    const int idx = r * 4 + sl4;
    src[r] = (idx < deg) ? colidx[b0 + idx] : 0;
  }

  const s8v selfv = *(const s8v*)(Hbs + (size_t)nd * 32 + c0);

  f4v acc0 = {0.f, 0.f, 0.f, 0.f};
  f4v acc1 = {0.f, 0.f, 0.f, 0.f};

#pragma unroll
  for (int j0 = 0; j0 < 32; j0 += 8) {
    if (!__any(j0 < deg)) break;
    s8v v[8];
    float msk[8];
#pragma unroll
    for (int jj = 0; jj < 8; ++jj) {
      const int j = j0 + jj;  // compile-time
      int s = __shfl(src[j >> 2], q * 4 + (j & 3), 64);
      if (j >= deg) s = 0;    // padded -> row 0 (L2-hot)
      msk[jj] = (j < deg) ? 1.f : 0.f;
      v[jj] = *(const s8v*)(Hbs + (size_t)s * 32 + c0);
    }
#pragma unroll
    for (int jj = 0; jj < 8; ++jj) {
#pragma unroll
      for (int t = 0; t < 4; ++t) {
        acc0[t] += bf2f((u16)v[jj][t]) * msk[jj];
        acc1[t] += bf2f((u16)v[jj][t + 4]) * msk[jj];
      }
    }
  }

  for (int j0 = 32; __any(j0 < deg); j0 += 8) {  // rare deg>32 tail
    s8v v[8];
    float msk[8];
#pragma unroll
    for (int jj = 0; jj < 8; ++jj) {
      const int idx = j0 + jj;
      int s = (idx < deg) ? colidx[b0 + idx] : 0;
      msk[jj] = (idx < deg) ? 1.f : 0.f;
      v[jj] = *(const s8v*)(Hbs + (size_t)s * 32 + c0);
    }
#pragma unroll
    for (int jj = 0; jj < 8; ++jj) {
#pragma unroll
      for (int t = 0; t < 4; ++t) {
        acc0[t] += bf2f((u16)v[jj][t]) * msk[jj];
        acc1[t] += bf2f((u16)v[jj][t + 4]) * msk[jj];
      }
    }
  }

  if (valid) {
    const float inv = 1.0f / (float)(deg + 1);
    f4v o0, o1;
#pragma unroll
    for (int t = 0; t < 4; ++t) {
      o0[t] = (acc0[t] + bf2f((u16)selfv[t])) * inv;
      o1[t] = (acc1[t] + bf2f((u16)selfv[t + 4])) * inv;
    }
    float* po = OUT + (size_t)node * HID + slice * 32 + sl4 * 8;
    *(f4v*)(po) = o0;
    *(f4v*)(po + 4) = o1;
  }
}

extern "C" void kernel_launch(void* const* d_in, const int* in_sizes, int n_in,
                              void* d_out, int out_size, void* d_ws, size_t ws_size,
                              hipStream_t stream) {
  const float* X = (const float*)d_in[0];     // [N_NODES, HID]
  const int* EI = (const int*)d_in[1];        // [2, N_EDGES]
  const float* W = (const float*)d_in[2];     // [HID, HID]
  const float* Bias = (const float*)d_in[3];  // [HID]

  float* OUT = (float*)d_out;

  // ws layout (bytes):
  //   Hb_t    @ 0          : 4*50000*32*2      = 12,800,000
  //   part    @ 12,800,000 : 391*2816*4        =  4,404,224
  //   colidx  @ 17,204,224 : 391*2816*4        =  4,404,224
  //   rp2     @ 21,608,448 : 50000*8           =    400,000
  //   pcnt    @ 22,008,448 : 391*32*4          =     50,048
  //   Wb      @ 22,058,496 : 16384*2           =     32,768
  char* ws = (char*)d_ws;
  u16* Hb = (u16*)(ws);
  unsigned* part = (unsigned*)(ws + 12800000);
  int* colidx = (int*)(ws + 17204224);
  int2* rp2 = (int2*)(ws + 21608448);
  int* pcnt = (int*)(ws + 22008448);
  u16* Wb = (u16*)(ws + 22058496);

  init_k<<<64 + (NP * PC_STRIDE + 255) / 256, 256, 0, stream>>>(W, Wb, pcnt);
  // fused (R10): blocks 0..127 = scatter; 128.. = MFMA gemm
  sg_k<<<P1_BLOCKS + GEMM_BLOCKS, 256, 0, stream>>>(EI, pcnt, part, X, Wb, Bias, Hb);
  p2csr_k<<<NP, 256, 0, stream>>>(part, pcnt, colidx, rp2);
  gather4_k<<<NSL * ((N_NODES + 63) / 64), 256, 0, stream>>>(Hb, colidx, rp2, OUT);
}

// Round 18
// 82.489 us; speedup vs baseline: 7.7473x; 1.0759x over previous
//
#include <hip/hip_runtime.h>

#define N_NODES 50000
#define N_EDGES 800000
#define HID 128
#define NP 391           // node partitions of 128 nodes
#define CAPP 2816        // partition capacity: mean 2048 + 17 sigma
#define PC_STRIDE 32     // pcnt padding: 128B per counter
#define P1_BLOCKS 128
#define EPB 6250         // edges per pass-A block (128*6250 = 800000)
#define NCO 8            // coarse buckets (6250 nodes each)
#define CAP1 1072        // per (block,coarse) capacity: mean 781 + 11 sigma
#define GEMM_BLOCKS ((N_NODES + 63) / 64)  // 782
#define NSL 4            // column slices (32 cols each)
#define SLICE4_U16 ((size_t)N_NODES * 32)

typedef float f4v __attribute__((ext_vector_type(4)));
typedef short s8v __attribute__((ext_vector_type(8)));
typedef unsigned short u16;

__device__ __forceinline__ u16 f2bf(float f) {  // RNE fp32 -> bf16
  union { float f; unsigned u; } v;
  v.f = f;
  const unsigned r = v.u + 0x7FFFu + ((v.u >> 16) & 1u);
  return (u16)(r >> 16);
}
__device__ __forceinline__ float bf2f(u16 h) {
  union { unsigned u; float f; } v;
  v.u = ((unsigned)h) << 16;
  return v.f;
}

// ---------------- fused init: W fp32->bf16 (blocks 0..63) + zero pcnt ----------------
__global__ __launch_bounds__(256) void init_k(const float* __restrict__ W,
                                              u16* __restrict__ Wb,
                                              int* __restrict__ pcnt) {
  const int b = blockIdx.x;
  if (b < 64) {
    const int i = b * 256 + threadIdx.x;
    Wb[i] = f2bf(W[i]);
  } else {
    const int i = (b - 64) * 256 + threadIdx.x;
    if (i < NP * PC_STRIDE) pcnt[i] = 0;
  }
}

// ---------------- FUSED pass A: coarse-bin scatter (0..127, ZERO global atomics) + MFMA GEMM ----------------
// Each scatter block bins its 6250 edges into its PRIVATE region part1[b][c][CAP1]
// (c = dst/6250). LDS cursors only; dense same-XCD writes; single EI pass.
__global__ __launch_bounds__(256) void sg_k(const int* __restrict__ EI,
                                            unsigned* __restrict__ part1,
                                            int* __restrict__ cnt1,
                                            const float* __restrict__ X,
                                            const u16* __restrict__ Wb,
                                            const float* __restrict__ Bias,
                                            u16* __restrict__ Hb) {
  __shared__ int cur[NCO];
  if (blockIdx.x < P1_BLOCKS) {
    const int b = blockIdx.x;
    const int t = threadIdx.x;
    if (t < NCO) cur[t] = 0;
    __syncthreads();
    const int e0 = b * EPB;
    const int e1 = min(e0 + EPB, N_EDGES);
    for (int e = e0 + t; e < e1; e += 256) {
      const int dst = EI[e];            // row 0 = destination
      const int src = EI[N_EDGES + e];  // row 1 = source
      const int c = dst / 6250;         // 0..7 (magic-mul)
      const int pos = atomicAdd(&cur[c], 1);
      if (pos < CAP1)
        part1[(size_t)(b * NCO + c) * CAP1 + pos] =
            ((unsigned)src << 13) | (unsigned)(dst - c * 6250);
    }
    __syncthreads();
    if (t < NCO) cnt1[b * NCO + t] = min(cur[t], CAP1);
    return;
  }
  // ---- GEMM part: Hb_t[sl][row][32] = bf16(X @ W^T + bias) ----
  const int gb = blockIdx.x - P1_BLOCKS;
  const int lane = threadIdx.x & 63;
  const int wv = threadIdx.x >> 6;
  const int i0 = gb * 64 + wv * 16;
  const int r16 = lane & 15;
  const int kb = lane >> 4;

  int arow = i0 + r16;
  if (arow >= N_NODES) arow = N_NODES - 1;  // clamp reads; stores guarded

  s8v a[4];
#pragma unroll
  for (int kc = 0; kc < 4; ++kc) {
    const int k0 = kc * 32 + kb * 8;
    const float4 x0 = *(const float4*)(X + (size_t)arow * HID + k0);
    const float4 x1 = *(const float4*)(X + (size_t)arow * HID + k0 + 4);
    s8v tv;
    tv[0] = (short)f2bf(x0.x); tv[1] = (short)f2bf(x0.y);
    tv[2] = (short)f2bf(x0.z); tv[3] = (short)f2bf(x0.w);
    tv[4] = (short)f2bf(x1.x); tv[5] = (short)f2bf(x1.y);
    tv[6] = (short)f2bf(x1.z); tv[7] = (short)f2bf(x1.w);
    a[kc] = tv;
  }

  f4v acc[8];
#pragma unroll
  for (int jt = 0; jt < 8; ++jt) acc[jt] = (f4v){0.f, 0.f, 0.f, 0.f};

#pragma unroll
  for (int jt = 0; jt < 8; ++jt) {
    const int j = jt * 16 + r16;
#pragma unroll
    for (int kc = 0; kc < 4; ++kc) {
      const int k0 = kc * 32 + kb * 8;
      const s8v bb = *(const s8v*)(Wb + (size_t)j * HID + k0);
      acc[jt] = __builtin_amdgcn_mfma_f32_16x16x32_bf16(a[kc], bb, acc[jt], 0, 0, 0);
    }
  }

#pragma unroll
  for (int jt = 0; jt < 8; ++jt) {
    const int sl = jt >> 1;
    const int c = (jt & 1) * 16 + r16;  // col within 32-col slice
    const float bias = Bias[jt * 16 + r16];
#pragma unroll
    for (int r = 0; r < 4; ++r) {
      const int row = i0 + kb * 4 + r;
      if (row < N_NODES)
        Hb[(size_t)sl * SLICE4_U16 + (size_t)row * 32 + c] = f2bf(acc[jt][r] + bias);
    }
  }
}

// ---------------- pass B: XCD-local fine binning into part ----------------
// c = blockIdx&7 -> XCD c (round-robin). 32 blocks per coarse, 4 regions each.
// Partition sub-range of coarse c (<=50 partitions, 550KB) stays in ONE L2;
// pcnt reservation depth 32 (was 128 global).
__global__ __launch_bounds__(256) void pb_k(const unsigned* __restrict__ part1,
                                            const int* __restrict__ cnt1,
                                            int* __restrict__ pcnt,
                                            unsigned* __restrict__ part) {
  __shared__ int hist[52], base[52];
  const int c = blockIdx.x & 7;
  const int g = blockIdx.x >> 3;  // 0..31
  const int t = threadIdx.x;
  const int pbase = (c * 6250) >> 7;
  const int plast = ((c + 1) * 6250 - 1) >> 7;
  const int npl = plast - pbase + 1;  // <= 50
  if (t < 52) hist[t] = 0;
  __syncthreads();
#pragma unroll
  for (int rb = 0; rb < 4; ++rb) {
    const int b = g * 4 + rb;
    const int n = cnt1[b * NCO + c];
    const unsigned* rg = part1 + (size_t)(b * NCO + c) * CAP1;
    for (int i = t; i < n; i += 256) {
      const int dst = (int)(rg[i] & 8191u) + c * 6250;
      atomicAdd(&hist[(dst >> 7) - pbase], 1);
    }
  }
  __syncthreads();
  if (t < npl) {
    const int h = hist[t];
    int bs = 0;
    if (h > 0) bs = atomicAdd(pcnt + (pbase + t) * PC_STRIDE, h);
    base[t] = (pbase + t) * CAPP + min(bs, CAPP);
    hist[t] = 0;  // reuse as cursor
  }
  __syncthreads();
#pragma unroll
  for (int rb = 0; rb < 4; ++rb) {
    const int b = g * 4 + rb;
    const int n = cnt1[b * NCO + c];
    const unsigned* rg = part1 + (size_t)(b * NCO + c) * CAP1;
    for (int i = t; i < n; i += 256) {
      const unsigned v = rg[i];
      const int dst = (int)(v & 8191u) + c * 6250;
      const int src = (int)(v >> 13);
      const int lp = (dst >> 7) - pbase;
      const int pos = atomicAdd(&hist[lp], 1);
      const int gpos = base[lp] + pos;
      if (gpos < (pbase + lp + 1) * CAPP)
        part[gpos] = ((unsigned)src << 7) | (unsigned)(dst & 127);
    }
  }
}

// ---------------- per-partition CSR build (R10-exact) ----------------
__global__ __launch_bounds__(256) void p2csr_k(const unsigned* __restrict__ part,
                                               const int* __restrict__ pcnt,
                                               int* __restrict__ colidx,
                                               int2* __restrict__ rp2) {
  __shared__ int cnt[128], rs[129], cur[128];
  const int p = blockIdx.x;
  const int t = threadIdx.x;
  const int n0 = p * 128;
  const int nn = min(128, N_NODES - n0);
  const int gb = p * CAPP;
  const int ge = gb + min(pcnt[p * PC_STRIDE], CAPP);
  if (t < 128) cnt[t] = 0;
  __syncthreads();
  for (int i = gb + t; i < ge; i += 256) atomicAdd(&cnt[part[i] & 127u], 1);
  __syncthreads();
  if (t == 0) {
    int acc = 0;
    for (int i = 0; i < 128; ++i) { rs[i] = acc; acc += cnt[i]; }
    rs[128] = acc;
  }
  __syncthreads();
  if (t < 128) cur[t] = rs[t];
  if (t < nn) rp2[n0 + t] = make_int2(gb + rs[t], cnt[t]);
  __syncthreads();
  for (int i = gb + t; i < ge; i += 256) {
    const unsigned v = part[i];
    const int pos = atomicAdd(&cur[v & 127u], 1);
    colidx[gb + pos] = (int)(v >> 7);
  }
}

// ---------------- sliced CSR gather (R10-exact) ----------------
__global__ __launch_bounds__(256) void gather4_k(const u16* __restrict__ Hb,
                                                 const int* __restrict__ colidx,
                                                 const int2* __restrict__ rp2,
                                                 float* __restrict__ OUT) {
  const int slice = blockIdx.x & 3;
  const int nb = blockIdx.x >> 2;
  const int wv = threadIdx.x >> 6;
  const int lane = threadIdx.x & 63;
  const int q = lane >> 2;   // node slot within wave (0..15)
  const int sl4 = lane & 3;  // lane within node group
  const int node = (nb * 4 + wv) * 16 + q;
  const bool valid = node < N_NODES;
  const int nd = valid ? node : 0;
  const int2 bd = rp2[nd];
  const int b0 = bd.x;
  const int deg = bd.y;
  const u16* Hbs = Hb + (size_t)slice * SLICE4_U16;
  const int c0 = sl4 * 8;  // u16 offset within 32-col slice (16B per lane)

  int src[8];
#pragma unroll
  for (int r = 0; r < 8; ++r) {
    const int idx = r * 4 + sl4;
    src[r] = (idx < deg) ? colidx[b0 + idx] : 0;
  }

  const s8v selfv = *(const s8v*)(Hbs + (size_t)nd * 32 + c0);

  f4v acc0 = {0.f, 0.f, 0.f, 0.f};
  f4v acc1 = {0.f, 0.f, 0.f, 0.f};

#pragma unroll
  for (int j0 = 0; j0 < 32; j0 += 8) {
    if (!__any(j0 < deg)) break;
    s8v v[8];
    float msk[8];
#pragma unroll
    for (int jj = 0; jj < 8; ++jj) {
      const int j = j0 + jj;  // compile-time
      int s = __shfl(src[j >> 2], q * 4 + (j & 3), 64);
      if (j >= deg) s = 0;    // padded -> row 0 (L2-hot)
      msk[jj] = (j < deg) ? 1.f : 0.f;
      v[jj] = *(const s8v*)(Hbs + (size_t)s * 32 + c0);
    }
#pragma unroll
    for (int jj = 0; jj < 8; ++jj) {
#pragma unroll
      for (int t = 0; t < 4; ++t) {
        acc0[t] += bf2f((u16)v[jj][t]) * msk[jj];
        acc1[t] += bf2f((u16)v[jj][t + 4]) * msk[jj];
      }
    }
  }

  for (int j0 = 32; __any(j0 < deg); j0 += 8) {  // rare deg>32 tail
    s8v v[8];
    float msk[8];
#pragma unroll
    for (int jj = 0; jj < 8; ++jj) {
      const int idx = j0 + jj;
      int s = (idx < deg) ? colidx[b0 + idx] : 0;
      msk[jj] = (idx < deg) ? 1.f : 0.f;
      v[jj] = *(const s8v*)(Hbs + (size_t)s * 32 + c0);
    }
#pragma unroll
    for (int jj = 0; jj < 8; ++jj) {
#pragma unroll
      for (int t = 0; t < 4; ++t) {
        acc0[t] += bf2f((u16)v[jj][t]) * msk[jj];
        acc1[t] += bf2f((u16)v[jj][t + 4]) * msk[jj];
      }
    }
  }

  if (valid) {
    const float inv = 1.0f / (float)(deg + 1);
    f4v o0, o1;
#pragma unroll
    for (int t = 0; t < 4; ++t) {
      o0[t] = (acc0[t] + bf2f((u16)selfv[t])) * inv;
      o1[t] = (acc1[t] + bf2f((u16)selfv[t + 4])) * inv;
    }
    float* po = OUT + (size_t)node * HID + slice * 32 + sl4 * 8;
    *(f4v*)(po) = o0;
    *(f4v*)(po + 4) = o1;
  }
}

extern "C" void kernel_launch(void* const* d_in, const int* in_sizes, int n_in,
                              void* d_out, int out_size, void* d_ws, size_t ws_size,
                              hipStream_t stream) {
  const float* X = (const float*)d_in[0];     // [N_NODES, HID]
  const int* EI = (const int*)d_in[1];        // [2, N_EDGES]
  const float* W = (const float*)d_in[2];     // [HID, HID]
  const float* Bias = (const float*)d_in[3];  // [HID]

  float* OUT = (float*)d_out;

  // ws layout (bytes):
  //   Hb_t          @ 0          : 4*50000*32*2    = 12,800,000
  //   part1/colidx  @ 12,800,000 : max(128*8*1072, 391*2816)*4 = 4,404,224
  //                                (part1 dead after pb_k; colidx reuses it)
  //   part          @ 17,204,224 : 391*2816*4      =  4,404,224
  //   rp2           @ 21,608,448 : 50000*8         =    400,000
  //   pcnt          @ 22,008,448 : 391*32*4        =     50,048
  //   cnt1          @ 22,058,496 : 128*8*4         =      4,096
  //   Wb            @ 22,062,592 : 16384*2         =     32,768  (end 22,095,360)
  char* ws = (char*)d_ws;
  u16* Hb = (u16*)(ws);
  unsigned* part1 = (unsigned*)(ws + 12800000);
  int* colidx = (int*)(ws + 12800000);  // aliases part1 (dead by then)
  unsigned* part = (unsigned*)(ws + 17204224);
  int2* rp2 = (int2*)(ws + 21608448);
  int* pcnt = (int*)(ws + 22008448);
  int* cnt1 = (int*)(ws + 22058496);
  u16* Wb = (u16*)(ws + 22062592);

  init_k<<<64 + (NP * PC_STRIDE + 255) / 256, 256, 0, stream>>>(W, Wb, pcnt);
  // pass A fused: blocks 0..127 = coarse-bin scatter (no global atomics); 128.. = gemm
  sg_k<<<P1_BLOCKS + GEMM_BLOCKS, 256, 0, stream>>>(EI, part1, cnt1, X, Wb, Bias, Hb);
  // pass B: XCD-local fine binning
  pb_k<<<256, 256, 0, stream>>>(part1, cnt1, pcnt, part);
  p2csr_k<<<NP, 256, 0, stream>>>(part, pcnt, colidx, rp2);
  gather4_k<<<NSL * ((N_NODES + 63) / 64), 256, 0, stream>>>(Hb, colidx, rp2, OUT);
}